// Round 1
// baseline (98.829 us; speedup 1.0000x reference)
//
#include <hip/hip_runtime.h>
#include <hip/hip_bf16.h>
#include <math.h>

#define N    8192
#define DIM  64
#define KSEL 32

// ---------------------------------------------------------------------------
// Kernel A: v = tanh(3 * (emb[idx] @ W^T + b))   for emb1->v1 and emb2->v2
// block = 256 threads; each block: 16 rows x 64 dims of one matrix.
// grid.x = 2*N/16 = 1024 ; blockIdx.x&1 selects matrix.
// ---------------------------------------------------------------------------
__global__ __launch_bounds__(256) void embed_linear_tanh(
    const int*   __restrict__ idx,
    const float* __restrict__ emb1,
    const float* __restrict__ emb2,
    const float* __restrict__ W,     // [DIM][DIM], out[d] = dot(e, W[d,:]) + b[d]
    const float* __restrict__ b,
    float* __restrict__ v1,
    float* __restrict__ v2)
{
    __shared__ float Wp[DIM][DIM + 1];   // +1 pad: lane l reads Wp[l][k] -> bank (l+k)%32, 2-way = free
    __shared__ float e[16][DIM];         // broadcast reads (same addr per wave) -> no pad needed

    const int t = threadIdx.x;
    const int m = blockIdx.x & 1;                 // 0: emb1->v1, 1: emb2->v2
    const int rowbase = (blockIdx.x >> 1) * 16;
    const float* emb  = m ? emb2 : emb1;
    float*       vout = m ? v2   : v1;

    // stage W (4096 floats): 256 threads * 4 float4
    {
        const float4* W4 = (const float4*)W;
        #pragma unroll
        for (int s = 0; s < 4; ++s) {
            int e4 = t + s * 256;          // 0..1023
            float4 wv = W4[e4];
            int d = e4 >> 4;
            int k = (e4 & 15) * 4;
            Wp[d][k]   = wv.x; Wp[d][k+1] = wv.y;
            Wp[d][k+2] = wv.z; Wp[d][k+3] = wv.w;
        }
    }
    // stage 16 gathered emb rows (1024 floats): thread t -> row t>>4, float4 seg t&15
    {
        int r = t >> 4, seg = t & 15;
        int g = idx[rowbase + r];
        float4 x = ((const float4*)(emb + (size_t)g * DIM))[seg];
        e[r][seg*4]   = x.x; e[r][seg*4+1] = x.y;
        e[r][seg*4+2] = x.z; e[r][seg*4+3] = x.w;
    }
    __syncthreads();

    const int d  = t & 63;   // output dim (= lane)
    const int r0 = t >> 6;   // wave index
    const float bias = b[d];
    #pragma unroll
    for (int rr = 0; rr < 4; ++rr) {
        int r = r0 + rr * 4;               // local row; same r across a wave -> e[] broadcast
        float acc = bias;
        #pragma unroll
        for (int k = 0; k < DIM; ++k) acc += e[r][k] * Wp[d][k];
        vout[(size_t)(rowbase + r) * DIM + d] = tanhf(3.0f * acc);
    }
}

// ---------------------------------------------------------------------------
// Kernel B: per row i, find the 32 lowest columns j with
//   relu(tanh(3*(v1_i.v2_j - v2_i.v1_j))) == 1.0f  (fp32-saturated tanh),
// which equals jax.lax.top_k(adj,32) + sort (ties at 1.0 break to low index).
// One wave per row; 4 waves/block; 64-column LDS-staged chunks; early exit.
// Serial exact top-k fallback if a row has <32 saturated entries (P ~ 0).
// ---------------------------------------------------------------------------
__global__ __launch_bounds__(256) void build_graph(
    const float* __restrict__ v1,
    const float* __restrict__ v2,
    float* __restrict__ out_rows,
    float* __restrict__ out_cols,
    float* __restrict__ out_data)
{
    // float4 [k4][col] layout: lane l reads c?v[k4][l] -> word addr (k4*64+l)*4,
    // start banks 4*l%32 distinct within each 8-lane phase group -> conflict-free b128.
    __shared__ float4 c1v[16][64];
    __shared__ float4 c2v[16][64];
    __shared__ float4 vi1[4][16];   // row-i vectors, broadcast-read per wave
    __shared__ float4 vi2[4][16];
    __shared__ int    colbuf[4][KSEL];
    __shared__ int    wdone[4];

    const int t = threadIdx.x;
    const int w = t >> 6;        // wave = which row of this block
    const int l = t & 63;        // lane
    const int i = blockIdx.x * 4 + w;

    if (l < 16) {
        vi1[w][l] = ((const float4*)(v1 + (size_t)i * DIM))[l];
        vi2[w][l] = ((const float4*)(v2 + (size_t)i * DIM))[l];
    }
    if (l == 0) wdone[w] = 0;
    __syncthreads();

    int  cnt  = 0;
    bool done = false;
    const int r = t >> 2;        // staging: column row 0..63
    const int q = t & 3;         // staging: 64B segment within row

    for (int cc = 0; cc < N / 64; ++cc) {
        const int jbase = cc * 64;
        // ---- cooperative staging: 64 column rows of v1,v2 -> LDS ----
        {
            const float4* p1 = (const float4*)(v1 + (size_t)(jbase + r) * DIM) + q * 4;
            const float4* p2 = (const float4*)(v2 + (size_t)(jbase + r) * DIM) + q * 4;
            #pragma unroll
            for (int s = 0; s < 4; ++s) {
                c1v[q * 4 + s][r] = p1[s];
                c2v[q * 4 + s][r] = p2[s];
            }
        }
        __syncthreads();
        // ---- compute: lane l handles column j = jbase + l ----
        if (!done) {
            float d1 = 0.f, d2 = 0.f;
            #pragma unroll
            for (int k4 = 0; k4 < 16; ++k4) {
                float4 a1 = vi1[w][k4];     // broadcast
                float4 b2 = c2v[k4][l];
                d1 += a1.x * b2.x + a1.y * b2.y + a1.z * b2.z + a1.w * b2.w;
                float4 a2 = vi2[w][k4];     // broadcast
                float4 b1 = c1v[k4][l];
                d2 += a2.x * b1.x + a2.y * b1.y + a2.z * b1.z + a2.w * b1.w;
            }
            float a    = d1 - d2;
            float adjv = tanhf(3.0f * a);
            bool  sat  = (adjv == 1.0f);                 // fp32 tanh saturation
            unsigned long long mask = __ballot(sat);
            int rank = (int)__popcll(mask & ((1ull << l) - 1ull));
            if (sat && (cnt + rank) < KSEL) colbuf[w][cnt + rank] = jbase + l;
            cnt += (int)__popcll(mask);
            if (cnt >= KSEL) { done = true; if (l == 0) wdone[w] = 1; }
        }
        __syncthreads();
        if (wdone[0] && wdone[1] && wdone[2] && wdone[3]) break;  // uniform
    }

    if (cnt >= KSEL) {
        if (l < KSEL) {
            int col = colbuf[w][l];          // ascending by construction
            size_t o = (size_t)i * KSEL + l;
            out_rows[o] = (float)i;
            out_cols[o] = (float)col;
            out_data[o] = 1.0f;              // saturated value, exact
        }
    } else if (l == 0) {
        // exact serial fallback: top-32 by (value desc, index asc), then col-sort.
        float bv[KSEL]; int bc[KSEL];
        #pragma unroll
        for (int k = 0; k < KSEL; ++k) { bv[k] = -1.0f; bc[k] = 0; }
        for (int j = 0; j < N; ++j) {
            float d1 = 0.f, d2 = 0.f;
            for (int k = 0; k < DIM; ++k) {
                d1 += v1[(size_t)i * DIM + k] * v2[(size_t)j * DIM + k];
                d2 += v2[(size_t)i * DIM + k] * v1[(size_t)j * DIM + k];
            }
            float adjv = fmaxf(tanhf(3.0f * (d1 - d2)), 0.0f);
            if (adjv > bv[KSEL - 1]) {       // strict: earlier equal index wins
                int p = KSEL - 1;
                while (p > 0 && bv[p - 1] < adjv) {
                    bv[p] = bv[p - 1]; bc[p] = bc[p - 1]; --p;
                }
                bv[p] = adjv; bc[p] = j;
            }
        }
        for (int x = 1; x < KSEL; ++x) {     // sort by column ascending
            float tv = bv[x]; int tc = bc[x]; int y = x - 1;
            while (y >= 0 && bc[y] > tc) { bv[y+1] = bv[y]; bc[y+1] = bc[y]; --y; }
            bv[y + 1] = tv; bc[y + 1] = tc;
        }
        for (int k = 0; k < KSEL; ++k) {
            size_t o = (size_t)i * KSEL + k;
            out_rows[o] = (float)i;
            out_cols[o] = (float)bc[k];
            out_data[o] = bv[k];
        }
    }
}

// ---------------------------------------------------------------------------
extern "C" void kernel_launch(void* const* d_in, const int* in_sizes, int n_in,
                              void* d_out, int out_size, void* d_ws, size_t ws_size,
                              hipStream_t stream) {
    const int*   idx  = (const int*)  d_in[0];
    const float* emb1 = (const float*)d_in[1];
    const float* emb2 = (const float*)d_in[2];
    const float* w1   = (const float*)d_in[3];
    const float* b1   = (const float*)d_in[4];
    // d_in[5], d_in[6] = lin2_w / lin2_b -- unused by the reference (faithful).

    float* v1 = (float*)d_ws;                  // [N][DIM] fp32
    float* v2 = v1 + (size_t)N * DIM;          // [N][DIM] fp32  (4 MB total)

    float* out      = (float*)d_out;           // [2*N*K index | N*K data], all fp32
    float* out_rows = out;
    float* out_cols = out + (size_t)N * KSEL;
    float* out_data = out + (size_t)2 * N * KSEL;

    embed_linear_tanh<<<2 * N / 16, 256, 0, stream>>>(idx, emb1, emb2, w1, b1, v1, v2);
    build_graph<<<N / 4, 256, 0, stream>>>(v1, v2, out_rows, out_cols, out_data);
}

// Round 2
// 93.463 us; speedup vs baseline: 1.0574x; 1.0574x over previous
//
#include <hip/hip_runtime.h>
#include <hip/hip_bf16.h>
#include <math.h>

#define N    8192
#define DIM  64
#define KSEL 32

// ---------------------------------------------------------------------------
// Kernel A: v = tanh(3 * (emb[idx] @ W^T + b))   for emb1->v1 and emb2->v2
// block = 256 threads; each block: 16 rows x 64 dims of one matrix.
// grid.x = 2*N/16 = 1024 ; blockIdx.x&1 selects matrix.
// ---------------------------------------------------------------------------
__global__ __launch_bounds__(256) void embed_linear_tanh(
    const int*   __restrict__ idx,
    const float* __restrict__ emb1,
    const float* __restrict__ emb2,
    const float* __restrict__ W,     // [DIM][DIM], out[d] = dot(e, W[d,:]) + b[d]
    const float* __restrict__ b,
    float* __restrict__ v1,
    float* __restrict__ v2)
{
    __shared__ float Wp[DIM][DIM + 1];   // +1 pad: lane l reads Wp[l][k] -> bank (l+k)%32, 2-way = free
    __shared__ float e[16][DIM];         // broadcast reads (same addr per wave) -> no pad needed

    const int t = threadIdx.x;
    const int m = blockIdx.x & 1;                 // 0: emb1->v1, 1: emb2->v2
    const int rowbase = (blockIdx.x >> 1) * 16;
    const float* emb  = m ? emb2 : emb1;
    float*       vout = m ? v2   : v1;

    // stage W (4096 floats): 256 threads * 4 float4
    {
        const float4* W4 = (const float4*)W;
        #pragma unroll
        for (int s = 0; s < 4; ++s) {
            int e4 = t + s * 256;          // 0..1023
            float4 wv = W4[e4];
            int d = e4 >> 4;
            int k = (e4 & 15) * 4;
            Wp[d][k]   = wv.x; Wp[d][k+1] = wv.y;
            Wp[d][k+2] = wv.z; Wp[d][k+3] = wv.w;
        }
    }
    // stage 16 gathered emb rows (1024 floats): thread t -> row t>>4, float4 seg t&15
    {
        int r = t >> 4, seg = t & 15;
        int g = idx[rowbase + r];
        float4 x = ((const float4*)(emb + (size_t)g * DIM))[seg];
        e[r][seg*4]   = x.x; e[r][seg*4+1] = x.y;
        e[r][seg*4+2] = x.z; e[r][seg*4+3] = x.w;
    }
    __syncthreads();

    const int d  = t & 63;   // output dim (= lane)
    const int r0 = t >> 6;   // wave index
    const float bias = b[d];
    #pragma unroll
    for (int rr = 0; rr < 4; ++rr) {
        int r = r0 + rr * 4;               // local row; same r across a wave -> e[] broadcast
        float acc = bias;
        #pragma unroll
        for (int k = 0; k < DIM; ++k) acc += e[r][k] * Wp[d][k];
        vout[(size_t)(rowbase + r) * DIM + d] = tanhf(3.0f * acc);
    }
}

// ---------------------------------------------------------------------------
// Kernel B v2: register-tiled column census.
// Per row i, find the 32 lowest columns j with tanhf(3*a[i,j]) == 1.0f
// (== jax top_k(adj,32)+sort: ties at 1.0 break to lowest index).
//
// Block = 256 threads (4 waves); each wave owns 4 rows -> 16 rows/block,
// grid = 512. Per 64-column chunk: block stages v1/v2 column rows into LDS
// ([k4][col] float4, conflict-free b128), each lane pulls ITS column into
// 128 VGPRs ONCE, then loops the wave's 4 rows reading only broadcast vi
// from LDS. Column LDS reads amortized 4x vs one-row-per-wave.
// Serial exact top-k fallback if a row has <32 saturated entries (P ~ 0).
// ---------------------------------------------------------------------------
__global__ __launch_bounds__(256, 2) void build_graph(
    const float* __restrict__ v1,
    const float* __restrict__ v2,
    float* __restrict__ out_rows,
    float* __restrict__ out_cols,
    float* __restrict__ out_data)
{
    __shared__ float4 c1v[16][64];   // [k4][col] : lane l -> start bank 4l%32, conflict-free
    __shared__ float4 c2v[16][64];
    __shared__ float4 vi1[16][16];   // 16 block rows x 16 float4, broadcast-read
    __shared__ float4 vi2[16][16];
    __shared__ int    colbuf[16][KSEL];
    __shared__ int    wdone[4];

    const int t = threadIdx.x;
    const int w = t >> 6;            // wave 0..3
    const int l = t & 63;            // lane
    const int rowbase = blockIdx.x * 16;

    // stage the block's 16 row-vectors (v1,v2): thread t -> row t>>4, seg t&15
    {
        int r = t >> 4, seg = t & 15;
        vi1[r][seg] = ((const float4*)(v1 + (size_t)(rowbase + r) * DIM))[seg];
        vi2[r][seg] = ((const float4*)(v2 + (size_t)(rowbase + r) * DIM))[seg];
    }
    if (l == 0) wdone[w] = 0;
    __syncthreads();

    int  cnt[4] = {0, 0, 0, 0};      // per-row saturated-count (wave-uniform)
    bool done = false;
    const int r = t >> 2;            // staging: column row 0..63
    const int q = t & 3;             // staging: 64B segment within row

    for (int cc = 0; cc < N / 64; ++cc) {
        const int jbase = cc * 64;
        // ---- cooperative staging: 64 column rows of v1,v2 -> LDS ----
        {
            const float4* p1 = (const float4*)(v1 + (size_t)(jbase + r) * DIM) + q * 4;
            const float4* p2 = (const float4*)(v2 + (size_t)(jbase + r) * DIM) + q * 4;
            #pragma unroll
            for (int s = 0; s < 4; ++s) {
                c1v[q * 4 + s][r] = p1[s];
                c2v[q * 4 + s][r] = p2[s];
            }
        }
        __syncthreads();

        if (!done) {
            // pull column (jbase+l) into registers: 32 conflict-free b128
            float4 c1r[16], c2r[16];
            #pragma unroll
            for (int k4 = 0; k4 < 16; ++k4) { c1r[k4] = c1v[k4][l]; c2r[k4] = c2v[k4][l]; }

            bool all_done = true;
            #pragma unroll
            for (int rr = 0; rr < 4; ++rr) {
                if (cnt[rr] < KSEL) {                 // wave-uniform branch
                    const int wrow = w * 4 + rr;
                    float d1 = 0.f, d2 = 0.f;
                    #pragma unroll
                    for (int k4 = 0; k4 < 16; ++k4) {
                        float4 a1 = vi1[wrow][k4];    // broadcast
                        float4 b2 = c2r[k4];
                        d1 += a1.x * b2.x + a1.y * b2.y + a1.z * b2.z + a1.w * b2.w;
                        float4 a2 = vi2[wrow][k4];    // broadcast
                        float4 b1 = c1r[k4];
                        d2 += a2.x * b1.x + a2.y * b1.y + a2.z * b1.z + a2.w * b1.w;
                    }
                    float a    = d1 - d2;
                    float adjv = tanhf(3.0f * a);
                    bool  sat  = (adjv == 1.0f);      // fp32 tanh saturation
                    unsigned long long mask = __ballot(sat);
                    int rank = (int)__popcll(mask & ((1ull << l) - 1ull));
                    if (sat && (cnt[rr] + rank) < KSEL) colbuf[wrow][cnt[rr] + rank] = jbase + l;
                    cnt[rr] += (int)__popcll(mask);
                    if (cnt[rr] < KSEL) all_done = false;
                }
            }
            if (all_done) { done = true; if (l == 0) wdone[w] = 1; }
        }
        __syncthreads();
        if (wdone[0] && wdone[1] && wdone[2] && wdone[3]) break;  // uniform
    }

    #pragma unroll
    for (int rr = 0; rr < 4; ++rr) {
        const int wrow = w * 4 + rr;
        const int i = rowbase + wrow;
        if (cnt[rr] >= KSEL) {
            if (l < KSEL) {
                int col = colbuf[wrow][l];       // ascending by construction
                size_t o = (size_t)i * KSEL + l;
                out_rows[o] = (float)i;
                out_cols[o] = (float)col;
                out_data[o] = 1.0f;              // saturated value, exact
            }
        } else if (l == 0) {
            // exact serial fallback: top-32 by (value desc, index asc), then col-sort.
            float bv[KSEL]; int bc[KSEL];
            #pragma unroll
            for (int k = 0; k < KSEL; ++k) { bv[k] = -1.0f; bc[k] = 0; }
            for (int j = 0; j < N; ++j) {
                float d1 = 0.f, d2 = 0.f;
                for (int k = 0; k < DIM; ++k) {
                    d1 += v1[(size_t)i * DIM + k] * v2[(size_t)j * DIM + k];
                    d2 += v2[(size_t)i * DIM + k] * v1[(size_t)j * DIM + k];
                }
                float adjv = fmaxf(tanhf(3.0f * (d1 - d2)), 0.0f);
                if (adjv > bv[KSEL - 1]) {       // strict: earlier equal index wins
                    int p = KSEL - 1;
                    while (p > 0 && bv[p - 1] < adjv) {
                        bv[p] = bv[p - 1]; bc[p] = bc[p - 1]; --p;
                    }
                    bv[p] = adjv; bc[p] = j;
                }
            }
            for (int x = 1; x < KSEL; ++x) {     // sort by column ascending
                float tv = bv[x]; int tc = bc[x]; int y = x - 1;
                while (y >= 0 && bc[y] > tc) { bv[y+1] = bv[y]; bc[y+1] = bc[y]; --y; }
                bv[y + 1] = tv; bc[y + 1] = tc;
            }
            for (int k = 0; k < KSEL; ++k) {
                size_t o = (size_t)i * KSEL + k;
                out_rows[o] = (float)i;
                out_cols[o] = (float)bc[k];
                out_data[o] = bv[k];
            }
        }
    }
}

// ---------------------------------------------------------------------------
extern "C" void kernel_launch(void* const* d_in, const int* in_sizes, int n_in,
                              void* d_out, int out_size, void* d_ws, size_t ws_size,
                              hipStream_t stream) {
    const int*   idx  = (const int*)  d_in[0];
    const float* emb1 = (const float*)d_in[1];
    const float* emb2 = (const float*)d_in[2];
    const float* w1   = (const float*)d_in[3];
    const float* b1   = (const float*)d_in[4];
    // d_in[5], d_in[6] = lin2_w / lin2_b -- unused by the reference (faithful).

    float* v1 = (float*)d_ws;                  // [N][DIM] fp32
    float* v2 = v1 + (size_t)N * DIM;          // [N][DIM] fp32  (4 MB total)

    float* out      = (float*)d_out;           // [2*N*K index | N*K data], all fp32
    float* out_rows = out;
    float* out_cols = out + (size_t)N * KSEL;
    float* out_data = out + (size_t)2 * N * KSEL;

    embed_linear_tanh<<<2 * N / 16, 256, 0, stream>>>(idx, emb1, emb2, w1, b1, v1, v2);
    build_graph<<<N / 16, 256, 0, stream>>>(v1, v2, out_rows, out_cols, out_data);
}